// Round 17
// baseline (345.900 us; speedup 1.0000x reference)
//
#include <hip/hip_runtime.h>
#include <hip/hip_bf16.h>

// PermutationGenerator: B=8192, N=64, D=128, LATENT=256, TEMP=0.1, 20 Sinkhorn iters.
// d_in (ALL f32): [0] padded [B][64][128], [1] set_size int32 [B], [2] maskB (UNUSED),
//       [3] gumbel [B][64][64], [4] W1 [128][256], [5] b1 [256],
//       [6] W2 [256][64], [7] b2 [64]
// d_out f32: [0:8192] set_size, then permuted [B][64][128].
//
// R17: kernel A -> ZERO-BARRIER WAVE-PER-BATCH (64-thread blocks, grid 8192,
// 16KB LDS -> 10 blocks/CU, no __syncthreads anywhere in A).
//   The wave-local MLP pipeline (GEMM1' h^T, bpermute redistribution, GEMM2'
//   net^T, init) is HW-verified by the R6 pass (absmax 0.03125). Its two fatal
//   flaws are fixed: x now staged into a per-wave swizzled LDS tile with
//   coalesced 128B/thread loads (R6 used 64B-chunk global scatter -> 952MB
//   FETCH), and sinkhorn/GEMM3 live in kernel B (R11-verified, ~floor).
//   P0 is stored directly in B's wave layout (v4f @ P0[(mj*4+nr)*256+lane*4],
//   1KB/instr) so B's load is R11's verified coalesced pattern, no fix-up.
// B: R16 zero-barrier wave-per-batch sinkhorn+GEMM3; P0 load = R11 original.
// Lessons kept: no launch bound (R13 spill), coalesced weights (R12), clean
// 64B+ writes (R8/R11), no fusion (R14/R15).

typedef _Float16 h16;
typedef h16 h8 __attribute__((ext_vector_type(8)));
typedef __fp16 fp16x2 __attribute__((ext_vector_type(2)));
typedef float v4f __attribute__((ext_vector_type(4)));

template<int CTRL>
__device__ __forceinline__ float dppf(float x) {
  return __int_as_float(__builtin_amdgcn_update_dpp(
      0, __float_as_int(x), CTRL, 0xF, 0xF, true));
}
__device__ __forceinline__ float red16_sum(float x) {
  x += dppf<0xB1>(x);
  x += dppf<0x4E>(x);
  x += dppf<0x124>(x);
  x += dppf<0x128>(x);
  return x;
}
__device__ __forceinline__ float frcp(float x) { return __builtin_amdgcn_rcpf(x); }
__device__ __forceinline__ float bperm(int addr, float v) {
  return __int_as_float(__builtin_amdgcn_ds_bpermute(addr, __float_as_int(v)));
}
__device__ __forceinline__ h8 cvt8(v4f a, v4f b) {
  union { h8 v; fp16x2 p[4]; } u;
  u.p[0] = __builtin_amdgcn_cvt_pkrtz(a[0], a[1]);
  u.p[1] = __builtin_amdgcn_cvt_pkrtz(a[2], a[3]);
  u.p[2] = __builtin_amdgcn_cvt_pkrtz(b[0], b[1]);
  u.p[3] = __builtin_amdgcn_cvt_pkrtz(b[2], b[3]);
  return u.v;
}

// w1s[kk*8192 + col*32 + e] = W1[(kk*32+e)*256 + col]   (kk<4, col<256, e<32)
// w2s[kk*2048 + j*32 + e]   = W2[(kk*32+e)*64 + j]      (kk<8, j<64,  e<32)
__global__ __launch_bounds__(256) void prep_w(const float* __restrict__ W1,
                                              const float* __restrict__ W2,
                                              h16* __restrict__ w1s,
                                              h16* __restrict__ w2s) {
  int t = blockIdx.x * 256 + threadIdx.x;
  if (t < 128 * 256) {
    int row = t >> 8, col = t & 255;          // W1[row][col]
    int kk = row >> 5, e = row & 31;
    w1s[kk * 8192 + col * 32 + e] = (h16)W1[t];
  } else if (t < 128 * 256 + 256 * 64) {
    int t2 = t - 128 * 256;
    int row = t2 >> 6, j = t2 & 63;           // W2[row][j]
    int kk = row >> 5, e = row & 31;
    w2s[kk * 2048 + j * 32 + e] = (h16)W2[t2];
  }
}

// ============ Kernel A: wave-per-batch MLP + init, ZERO barriers =============
// One wave (64 threads) per batch. LDS: xh f16 [64][128] swizzled, 16384B.
template<bool WSF>
__global__ __launch_bounds__(64) void mlp_init_wave(
    const float* __restrict__ xf,
    const int* __restrict__ ssz,
    const float* __restrict__ gn,
    const float* __restrict__ b1,
    const float* __restrict__ b2,
    const h16* __restrict__ w1s,   // == W1^T coalesced: [kk<4][lat<256][e<32]
    const h16* __restrict__ w2s,   // == W2^T coalesced: [kk<8][j<64][e<32]
    const float* __restrict__ W1f,
    const float* __restrict__ W2f,
    float* __restrict__ outp) {
  __shared__ __align__(16) char smem[16384];

  const int lane = threadIdx.x;
  const int g = lane >> 4, lc = lane & 15;
  const int b = blockIdx.x;
  const int k = ssz[b];
  const int mcnt = (k + 15) >> 4;
  const float* xb = xf + (size_t)b * 8192;

  // ---- stage x -> swizzled f16 LDS (coalesced 128B/lane per pass; no barrier:
  //      same wave writes then reads, lgkmcnt auto-ordered)
#pragma unroll
  for (int p4 = 0; p4 < 4; ++p4) {
    const int r = 16 * p4 + (lane >> 2);
    const int s = lane & 3;
    const float* src = xb + r * 128 + s * 32;
#pragma unroll
    for (int u = 0; u < 4; ++u) {
      const int byte = (r * 256 + (s * 32 + u * 8) * 2) ^ ((r & 7) << 4);
      *(h8*)(smem + byte) =
          cvt8(*(const v4f*)(src + u * 8), *(const v4f*)(src + u * 8 + 4));
    }
  }

  // bpermute source lanes for h^T D-frag -> B-frag redistribution (R6-verified)
  const int srcA = ((2 * (g & 1)) * 16 + lc) * 4;  // elems 0..3
  const int srcB = srcA + 64;                      // elems 4..7

  // p[mj][nr][q] accumulates net^T: = net[r=16nr+lc][j=16mj+4g+q]
  v4f p[4][4];
#pragma unroll
  for (int mj = 0; mj < 4; ++mj)
#pragma unroll
    for (int nr = 0; nr < 4; ++nr) p[mj][nr] = (v4f){0.f, 0.f, 0.f, 0.f};

  // ---- MLP: 8 slabs of 32 latents; GEMM1' from LDS-x + coalesced w1s;
  //      bpermute h^T; GEMM2' partial with coalesced w2s. (R6-verified flow)
#pragma unroll 1
  for (int lb = 0; lb < 8; ++lb) {
    v4f accT[2][4];
#pragma unroll
    for (int mt = 0; mt < 2; ++mt)
#pragma unroll
      for (int nr = 0; nr < 4; ++nr) accT[mt][nr] = (v4f){0.f, 0.f, 0.f, 0.f};

#pragma unroll
    for (int kk = 0; kk < 4; ++kk) {
      h8 aw[2];
#pragma unroll
      for (int mt = 0; mt < 2; ++mt) {
        if (WSF) {
          aw[mt] = *(const h8*)&w1s[kk * 8192 + (lb * 32 + 16 * mt + lc) * 32 + 8 * g];
        } else {
          h8 t;
#pragma unroll
          for (int e = 0; e < 8; ++e)
            t[e] = (h16)W1f[(kk * 32 + 8 * g + e) * 256 + lb * 32 + 16 * mt + lc];
          aw[mt] = t;
        }
      }
#pragma unroll
      for (int nr = 0; nr < 4; ++nr)
        if (nr < mcnt) {
          const int row = 16 * nr + lc;
          const int byte = (row * 256 + (kk * 32 + 8 * g) * 2) ^ ((row & 7) << 4);
          h8 bx = *(const h8*)(smem + byte);
          accT[0][nr] = __builtin_amdgcn_mfma_f32_16x16x32_f16(aw[0], bx, accT[0][nr], 0, 0, 0);
          accT[1][nr] = __builtin_amdgcn_mfma_f32_16x16x32_f16(aw[1], bx, accT[1][nr], 0, 0, 0);
        }
    }

    // bias + relu -> h^T D-frags (ht[mt][nr][q] = h^T[lb*32+16mt+4g+q][16nr+lc])
    v4f b1a = *(const v4f*)&b1[lb * 32 + 4 * g];
    v4f b1b = *(const v4f*)&b1[lb * 32 + 16 + 4 * g];
    float ht0[4][4], ht1[4][4];
#pragma unroll
    for (int nr = 0; nr < 4; ++nr)
      if (nr < mcnt)
#pragma unroll
        for (int q = 0; q < 4; ++q) {
          ht0[nr][q] = fmaxf(accT[0][nr][q] + b1a[q], 0.0f);
          ht1[nr][q] = fmaxf(accT[1][nr][q] + b1b[q], 0.0f);
        }

    // GEMM2' partial: A = W2^T rows j (coalesced), B = h^T via bpermute
    h8 aj[4];
#pragma unroll
    for (int mj = 0; mj < 4; ++mj)
      if (mj < mcnt) {
        if (WSF) {
          aj[mj] = *(const h8*)&w2s[lb * 2048 + (16 * mj + lc) * 32 + 8 * g];
        } else {
          h8 t;
#pragma unroll
          for (int e = 0; e < 8; ++e)
            t[e] = (h16)W2f[(lb * 32 + 8 * g + e) * 64 + 16 * mj + lc];
          aj[mj] = t;
        }
      }
#pragma unroll
    for (int nr = 0; nr < 4; ++nr)
      if (nr < mcnt) {
        float hv[8];
#pragma unroll
        for (int e = 0; e < 8; ++e) {
          const int a_ = (e < 4) ? srcA : srcB;
          float v0 = bperm(a_, ht0[nr][e & 3]);
          float v1 = bperm(a_, ht1[nr][e & 3]);
          hv[e] = (g >= 2) ? v1 : v0;
        }
        h8 bh = cvt8((v4f){hv[0], hv[1], hv[2], hv[3]},
                     (v4f){hv[4], hv[5], hv[6], hv[7]});
#pragma unroll
        for (int mj = 0; mj < 4; ++mj)
          if (mj < mcnt)
            p[mj][nr] = __builtin_amdgcn_mfma_f32_16x16x32_f16(aj[mj], bh, p[mj][nr], 0, 0, 0);
      }
  }

  // ---- init (R6-verified): la = net^T + b2 + gn; mask; rowmax over j; exp2
  v4f b2j[4];
#pragma unroll
  for (int mj = 0; mj < 4; ++mj) b2j[mj] = *(const v4f*)&b2[16 * mj + 4 * g];

#pragma unroll
  for (int nr = 0; nr < 4; ++nr)
    if (nr < mcnt) {
      const int r = 16 * nr + lc;
#pragma unroll
      for (int mj = 0; mj < 4; ++mj)
        if (mj < mcnt) {
          v4f gv = *(const v4f*)(gn + (size_t)b * 4096 + r * 64 + 16 * mj + 4 * g);
#pragma unroll
          for (int q = 0; q < 4; ++q) {
            const int j = 16 * mj + 4 * g + q;
            const float la = p[mj][nr][q] + b2j[mj][q] + gv[q];
            p[mj][nr][q] = (r < k && j < k) ? la : -1e30f;
          }
        }
      float m_ = -1e30f;
#pragma unroll
      for (int mj = 0; mj < 4; ++mj)
        if (mj < mcnt)
#pragma unroll
          for (int q = 0; q < 4; ++q) m_ = fmaxf(m_, p[mj][nr][q]);
      m_ = fmaxf(m_, __shfl_xor(m_, 16));
      m_ = fmaxf(m_, __shfl_xor(m_, 32));
#pragma unroll
      for (int mj = 0; mj < 4; ++mj)
        if (mj < mcnt)
#pragma unroll
          for (int q = 0; q < 4; ++q) {
            const float la = p[mj][nr][q];
            p[mj][nr][q] = (la > -1e29f) ? exp2f((la - m_) * 14.4269504089f) : 0.0f;
          }
    } else {
#pragma unroll
      for (int mj = 0; mj < 4; ++mj) p[mj][nr] = (v4f){0.f, 0.f, 0.f, 0.f};
    }

  // masked (mj>=mcnt) stay zero from accumulator init; ensure exact zeros:
#pragma unroll
  for (int mj = 0; mj < 4; ++mj)
    if (mj >= mcnt)
#pragma unroll
      for (int nr = 0; nr < 4; ++nr) p[mj][nr] = (v4f){0.f, 0.f, 0.f, 0.f};

  // ---- store P0 directly in B's wave layout: v4f @ P0[(mj*4+nr)*256+lane*4]
  //      (1KB per instruction, fully coalesced; B load = R11-verified pattern)
  float* P0 = outp + 8192 + (size_t)b * 8192;
#pragma unroll
  for (int mj = 0; mj < 4; ++mj)
#pragma unroll
    for (int nr = 0; nr < 4; ++nr)
      *(v4f*)&P0[(mj * 4 + nr) * 256 + lane * 4] = p[mj][nr];
}

// ================= Kernel B: wave-per-batch Sinkhorn + GEMM3, ZERO barriers ==
// Per-wave private 8KB pth: P^T subtiled [i>>3][j][i&7] f16 (conflict-free b128)
__global__ __launch_bounds__(256, 4) void sink_out(
    const float* __restrict__ xf,
    const int* __restrict__ ssz,
    float* __restrict__ outp) {
  __shared__ h16 pth_all[4][4096];

  const int tid = threadIdx.x;
  const int w = tid >> 6, lane = tid & 63, g = lane >> 4, lc = lane & 15;
  h16* pth = pth_all[w];

  const int b = blockIdx.x * 4 + w;
  const int k = ssz[b];
  const int mcnt = (k + 15) >> 4;
  const int kk3max = (k + 31) >> 5;
  const float* xb = xf + (size_t)b * 8192;

  if (lane == 0) outp[b] = (float)k;   // set_size

  // load P0 (R11-verified): p[mj][nr][q] = P[16nr+lc][16mj+4g+q]
  v4f p[4][4];
  {
    const float* P0 = outp + 8192 + (size_t)b * 8192;
#pragma unroll
    for (int mj = 0; mj < 4; ++mj)
#pragma unroll
      for (int nr = 0; nr < 4; ++nr)
        p[mj][nr] = *(const v4f*)&P0[((mj * 4 + nr) * 64 + lane) * 4];
  }

  // 20 Sinkhorn iterations, fully in-register, zero barriers
#pragma unroll 1
  for (int it = 0; it < 20; ++it) {
#pragma unroll
    for (int nr = 0; nr < 4; ++nr)
      if (nr < mcnt) {
        float s = 0.0f;
#pragma unroll
        for (int mj = 0; mj < 4; ++mj)
          if (mj < mcnt)
            s += (p[mj][nr][0] + p[mj][nr][1]) + (p[mj][nr][2] + p[mj][nr][3]);
        s += __shfl_xor(s, 16);
        s += __shfl_xor(s, 32);
        const float sc = frcp(s + 1e-30f);
#pragma unroll
        for (int mj = 0; mj < 4; ++mj)
          if (mj < mcnt) {
            p[mj][nr][0] *= sc; p[mj][nr][1] *= sc;
            p[mj][nr][2] *= sc; p[mj][nr][3] *= sc;
          }
      }
#pragma unroll
    for (int mj = 0; mj < 4; ++mj)
      if (mj < mcnt) {
#pragma unroll
        for (int q = 0; q < 4; ++q) {
          float c = 0.0f;
#pragma unroll
          for (int nr = 0; nr < 4; ++nr)
            if (nr < mcnt) c += p[mj][nr][q];
          c = red16_sum(c);
          const float sc = frcp(c + 1e-30f);
#pragma unroll
          for (int nr = 0; nr < 4; ++nr)
            if (nr < mcnt) p[mj][nr][q] *= sc;
        }
      }
  }

  // stage P^T: pth[(i>>3)*512 + j*8 + (i&7)], i = 16nr+lc, j = 16mj+4g+q
#pragma unroll
  for (int mj = 0; mj < 4; ++mj)
#pragma unroll
    for (int nr = 0; nr < 4; ++nr)
#pragma unroll
      for (int q = 0; q < 4; ++q)
        pth[((2 * nr + (lc >> 3)) * 64 + 16 * mj + 4 * g + q) * 8 + (lc & 7)] =
            (h16)p[mj][nr][q];
  asm volatile("s_waitcnt lgkmcnt(0)" ::: "memory");

  float* outb = outp + 8192 + (size_t)b * 8192;
#pragma unroll 1
  for (int c = 0; c < 4; ++c) {  // f-chunks of 32
    v4f acc3[4][2];
#pragma unroll
    for (int m = 0; m < 4; ++m)
#pragma unroll
      for (int nn = 0; nn < 2; ++nn) acc3[m][nn] = (v4f){0.f, 0.f, 0.f, 0.f};
#pragma unroll 1
    for (int kk = 0; kk < kk3max; ++kk) {
      h8 ap[4];
#pragma unroll
      for (int m = 0; m < 4; ++m)
        if (m < mcnt)
          ap[m] = *(const h8*)&pth[((4 * kk + g) * 64 + 16 * m + lc) * 8];
#pragma unroll
      for (int nn = 0; nn < 2; ++nn) {
        const int f = 16 * (2 * c + nn) + lc;
        v4f x0, x1;
#pragma unroll
        for (int e = 0; e < 4; ++e) x0[e] = xb[(kk * 32 + 8 * g + e) * 128 + f];
#pragma unroll
        for (int e = 0; e < 4; ++e) x1[e] = xb[(kk * 32 + 8 * g + 4 + e) * 128 + f];
        h8 bxx = cvt8(x0, x1);
#pragma unroll
        for (int m = 0; m < 4; ++m)
          if (m < mcnt)
            acc3[m][nn] = __builtin_amdgcn_mfma_f32_16x16x32_f16(ap[m], bxx, acc3[m][nn], 0, 0, 0);
      }
    }
#pragma unroll
    for (int m = 0; m < 4; ++m)
#pragma unroll
      for (int nn = 0; nn < 2; ++nn)
#pragma unroll
        for (int q = 0; q < 4; ++q)
          outb[(16 * m + 4 * g + q) * 128 + 16 * (2 * c + nn) + lc] = acc3[m][nn][q];
  }
}

extern "C" void kernel_launch(void* const* d_in, const int* in_sizes, int n_in,
                              void* d_out, int out_size, void* d_ws, size_t ws_size,
                              hipStream_t stream) {
  const float* xf = (const float*)d_in[0];
  const int* ssz = (const int*)d_in[1];
  // d_in[2] = maskB: unused (recomputed from set_size)
  const float* gn = (const float*)d_in[3];
  const float* W1 = (const float*)d_in[4];
  const float* b1 = (const float*)d_in[5];
  const float* W2 = (const float*)d_in[6];
  const float* b2 = (const float*)d_in[7];
  float* outp = (float*)d_out;

  const size_t ws_need = (size_t)(128 * 256 + 256 * 64) * sizeof(h16);  // 98304 B
  const bool use_ws = (d_ws != nullptr) && (ws_size >= ws_need);

  if (use_ws) {
    h16* w1s = (h16*)d_ws;             // [4][256][32] f16
    h16* w2s = w1s + 128 * 256;        // [8][64][32]  f16
    prep_w<<<192, 256, 0, stream>>>(W1, W2, w1s, w2s);
    mlp_init_wave<true><<<8192, 64, 0, stream>>>(xf, ssz, gn, b1, b2, w1s, w2s,
                                                 W1, W2, outp);
  } else {
    mlp_init_wave<false><<<8192, 64, 0, stream>>>(xf, ssz, gn, b1, b2,
                                                  (const h16*)nullptr,
                                                  (const h16*)nullptr,
                                                  W1, W2, outp);
  }
  sink_out<<<2048, 256, 0, stream>>>(xf, ssz, outp);
}